// Round 10
// baseline (329.392 us; speedup 1.0000x reference)
//
#include <hip/hip_runtime.h>

typedef unsigned short u16;
typedef unsigned int   u32;
typedef __bf16  bf16x8 __attribute__((ext_vector_type(8)));
typedef float   f32x4  __attribute__((ext_vector_type(4)));
typedef u16     u16x4  __attribute__((ext_vector_type(4)));
typedef u16     u16x8  __attribute__((ext_vector_type(8)));

#define S_LEN 2048
#define NH 32
#define NKVH 8
#define HD 128
#define QKVST 6144          /* packed QKV row stride  */
#define AOST  4096          /* attn-out row stride    */
#define ATT_SCALE 0.08838834764831845f
#define LOG2E 1.4426950408889634f
/* Q is pre-scaled by ATT_SCALE*LOG2E -> scores are log2-domain logits */
#define QSC2 (ATT_SCALE * LOG2E)
#define RESCALE_THR2 11.5f   /* = 8 nats in log2 units; P bounded by 2^11.5 */

__device__ __forceinline__ u16 f2bf(float f){
  u32 u = __builtin_bit_cast(u32, f);
  u += 0x7FFFu + ((u >> 16) & 1u);
  return (u16)(u >> 16);
}
__device__ __forceinline__ float bf2f(u16 h){
  u32 u = ((u32)h) << 16;
  return __builtin_bit_cast(float, u);
}
// async global->LDS, 16B per lane. Dest must be wave-uniform base + lane*16.
__device__ __forceinline__ void gload_lds16(const u16* g, u16* l){
  __builtin_amdgcn_global_load_lds(
      (const __attribute__((address_space(1))) void*)g,
      (__attribute__((address_space(3))) void*)l, 16, 0, 0);
}

// ------------- fused f32 -> bf16 convert of ALL inputs (one launch) --------
// ws layout is contiguous & source-ordered: XB | Wq | Wk | Wv | Wo
__global__ void cvt_all_kernel(const f32x4* __restrict__ hs, const f32x4* __restrict__ wq,
                               const f32x4* __restrict__ wk, const f32x4* __restrict__ wv,
                               const f32x4* __restrict__ wo, u16x4* __restrict__ out){
  int i = blockIdx.x * 256 + threadIdx.x;          // 0 .. 6291455
  const f32x4* src; int off;
  if      (i < 1048576){ src = hs; off = i; }
  else if (i < 3145728){ src = wq; off = i - 1048576; }
  else if (i < 3670016){ src = wk; off = i - 3145728; }
  else if (i < 4194304){ src = wv; off = i - 3670016; }
  else                 { src = wo; off = i - 4194304; }
  f32x4 v = src[off];
  u16x4 o;
  o[0] = f2bf(v[0]); o[1] = f2bf(v[1]); o[2] = f2bf(v[2]); o[3] = f2bf(v[3]);
  out[i] = o;
}

// ---------------- GEMM: C[M][N] = X[M][K] @ W[N][K]^T (bf16 in, f32 acc) ----
// 128(M) x BN(N) tile, BK=64 (2x 32-sub-tiles), double-buffered prefetch.
// BN=128: 4 waves 2x2, wave-tile 64x64. BN=64: 4 waves 2x2, wave-tile 64x32
// (for grids that would otherwise land at 1 block/CU, e.g. O-proj 2048x2048).
// ROPE=1 fuses partial RoPE (Q+K cols, n0<5120) and QSC2 (Q cols, n0<4096).
template<int OUT_BF16, int ROPE, int BN>
__global__ __launch_bounds__(256, 2)
void gemm_bt_kernel(const u16* __restrict__ X, const u16* __restrict__ W,
                    void* __restrict__ Cv, int M, int N, int K,
                    const float* __restrict__ cosv, const float* __restrict__ sinv){
  __shared__ __align__(16) u16 As[2][2][128 * 32];
  __shared__ __align__(16) u16 Bs[2][2][BN * 32];
  const int NJ = BN / 32;             // b-frags per wave
  const int m0 = blockIdx.y * 128, n0 = blockIdx.x * BN;
  const int tid = threadIdx.x;
  const int wave = tid >> 6, lane = tid & 63;
  const int wm = wave >> 1, wn = wave & 1;
  const int g = lane >> 4, ln = lane & 15;
  const int r0 = tid >> 2;            // rows 0..63 (tid*16B == linear LDS dest)
  const int cc = (tid & 3) * 8;       // bf16 col within sub-tile BK=32
  f32x4 acc[4][NJ] = {};
  const u16* xa0 = X + (size_t)(m0 + r0) * K + cc;
  const u16* xa1 = X + (size_t)(m0 + r0 + 64) * K + cc;
  const u16* wb0 = W + (size_t)(n0 + r0) * K + cc;
  const u16* wb1 = W + (size_t)(n0 + r0 + (BN == 128 ? 64 : 0)) * K + cc;

  auto stage = [&](int buf, int k0){
    #pragma unroll
    for (int s = 0; s < 2; s++){
      const int kc = k0 + s * 32;
      gload_lds16(xa0 + kc, &As[buf][s][tid * 8]);
      gload_lds16(xa1 + kc, &As[buf][s][2048 + tid * 8]);
      gload_lds16(wb0 + kc, &Bs[buf][s][tid * 8]);
      if (BN == 128) gload_lds16(wb1 + kc, &Bs[buf][s][2048 + tid * 8]);
    }
  };

  stage(0, 0);
  __syncthreads();                       // implicit vmcnt(0): tile 0 ready
  int cur = 0;
  for (int k0 = 0; k0 < K; k0 += 64){
    if (k0 + 64 < K) stage(cur ^ 1, k0 + 64);   // prefetch overlaps compute
    #pragma unroll
    for (int s = 0; s < 2; s++){
      bf16x8 a[4], b[NJ];
      #pragma unroll
      for (int f = 0; f < 4; f++) a[f] = *(const bf16x8*)&As[cur][s][(wm * 64 + f * 16 + ln) * 32 + g * 8];
      #pragma unroll
      for (int f = 0; f < NJ; f++) b[f] = *(const bf16x8*)&Bs[cur][s][(wn * (BN / 2) + f * 16 + ln) * 32 + g * 8];
      __builtin_amdgcn_s_setprio(1);
      #pragma unroll
      for (int i = 0; i < 4; i++)
        #pragma unroll
        for (int j = 0; j < NJ; j++)
          acc[i][j] = __builtin_amdgcn_mfma_f32_16x16x32_bf16(a[i], b[j], acc[i][j], 0, 0, 0);
      __builtin_amdgcn_s_setprio(0);
    }
    __syncthreads();   // ONE barrier/tile: drains prefetch vmcnt + guards reuse
    cur ^= 1;
  }
  if (ROPE && BN == 128){
    // fused partial RoPE: Q/K column blocks (n0<5120), first-half dims (wn==0)
    if (wn == 0 && n0 < 5120){
      #pragma unroll
      for (int i = 0; i < 4; i++)
        #pragma unroll
        for (int r = 0; r < 4; r++){
          const int row = m0 + wm * 64 + i * 16 + g * 4 + r;
          #pragma unroll
          for (int j = 0; j < 2; j++){
            const int d = j * 16 + ln;               // 0..31, partner d+32
            float c  = cosv[row * 64 + d];
            float sn = sinv[row * 64 + d];
            float x0 = acc[i][j][r], x1 = acc[i][j + 2][r];
            acc[i][j][r]     = x0 * c - x1 * sn;
            acc[i][j + 2][r] = x1 * c + x0 * sn;
          }
        }
    }
    // fold attention scale * log2(e) into Q: attn works in exp2 domain
    if (n0 < 4096){
      #pragma unroll
      for (int i = 0; i < 4; i++)
        #pragma unroll
        for (int j = 0; j < 4; j++)
          #pragma unroll
          for (int r = 0; r < 4; r++) acc[i][j][r] *= QSC2;
    }
  }
  // epilogue: C/D layout col = lane&15, row = (lane>>4)*4 + reg  [m89]
  #pragma unroll
  for (int i = 0; i < 4; i++)
    #pragma unroll
    for (int j = 0; j < NJ; j++)
      #pragma unroll
      for (int r = 0; r < 4; r++){
        int row = m0 + wm * 64 + i * 16 + g * 4 + r;
        int col = n0 + wn * (BN / 2) + j * 16 + ln;
        if (OUT_BF16) ((u16*)Cv)[(size_t)row * N + col] = f2bf(acc[i][j][r]);
        else          ((float*)Cv)[(size_t)row * N + col] = acc[i][j][r];
      }
}

// ---------------- V transpose: VT[kvh][vd][s] from packed QKV -------------
__global__ void vtrans_kernel(const u16* __restrict__ QKV, u16* __restrict__ VT){
  int idx = blockIdx.x * 256 + threadIdx.x;
  if (idx >= NKVH * HD * S_LEN) return;
  int s   = idx & (S_LEN - 1);
  int vd  = (idx >> 11) & (HD - 1);
  int kvh = idx >> 18;
  VT[idx] = QKV[(size_t)s * QKVST + 5120 + kvh * HD + vd];
}

// ---------------- causal flash attention with sink, GQA 4:1 ----------------
// R9 geometry (4 waves/block, 16 q-rows/wave, 1024 blocks, KVBLK=64) with
// K READ DIRECTLY FROM GLOBAL (L2-resident: kvh is XCD-aligned via b&7).
// Removes K staging + 32 of 112 ds_read_b128 per block-tile, shrinks LDS
// 76->40KB -> 3 blocks/CU (12 waves, +50% TLP vs R9's 8).
// Ordering: K-loads for tile t issue BEFORE the V-prefetch gload_lds of
// t+1 (vmcnt is in-order; reversed order would drain the prefetch at QK).
// l via register ones-B-frag; sink folded into init (m=sb2, L=1); exp2
// domain (Q pre-scaled by ATT_SCALE*log2e); defer-max; ONE barrier/tile.
__global__ __launch_bounds__(256, 3)
void attn_kernel(const u16* __restrict__ QKV, const u16* __restrict__ VT,
                 const float* __restrict__ sinkb, u16* __restrict__ AO){
  __shared__ __align__(16) u16 Vs[2][128 * 64];
  __shared__ __align__(16) u16 Ps[4][16 * 64];
  const int b   = blockIdx.x;
  const int kvh = b & 7;                 // XCD round-robin -> kvh per XCD
  const int h   = kvh * 4 + ((b >> 3) & 3);
  const int qt  = 31 - (b >> 5);         // longest blocks first
  const int tid = threadIdx.x;
  const int w = tid >> 6, lane = tid & 63;
  const int g = lane >> 4, ln = lane & 15;
  const int q0 = qt * 64;
  const int qw = q0 + w * 16;

  const u16* Vbase = VT + (size_t)kvh * HD * S_LEN;     // + vd*S_LEN + k
  // per-lane K gather base: row ln of K (L2-resident), col t*32 + g*8
  const u16* Kl = QKV + 4096 + kvh * HD + (size_t)ln * QKVST + g * 8;

  auto stage = [&](int buf, int kt){
    const int k0 = kt * 64;
    #pragma unroll
    for (int p = 0; p < 4; p++){
      int idx = p * 256 + tid;
      int vd = idx >> 3, c8 = idx & 7;
      gload_lds16(Vbase + (size_t)vd * S_LEN + k0 + ((c8 ^ (vd & 7)) * 8), &Vs[buf][idx * 8]);
    }
  };

  // register ones-B-frag for l accumulation: B[k][0] = 1 (lanes ln==0)
  u16x8 ob;
  #pragma unroll
  for (int j = 0; j < 8; j++) ob[j] = (ln == 0) ? (u16)0x3F80 : (u16)0;
  const bf16x8 onesf = __builtin_bit_cast(bf16x8, ob);

  // Q A-frags (pre-scaled by ATT_SCALE*log2e): row = ln, k = t*32 + g*8 + j
  bf16x8 qf[4];
  const u16* qrow = QKV + (size_t)(qw + ln) * QKVST + h * HD;
  #pragma unroll
  for (int t = 0; t < 4; t++) qf[t] = *(const bf16x8*)(qrow + t * 32 + g * 8);

  // sink folded into init: m = sb2; L (l-accum) starts at 1 in col 0.
  const float sb2 = sinkb[h] * LOG2E;
  f32x4 O[8] = {};
  f32x4 L;
  L[0] = L[1] = L[2] = L[3] = (ln == 0) ? 1.f : 0.f;
  float m_r[4];
  #pragma unroll
  for (int r = 0; r < 4; r++) m_r[r] = sb2;

  const int nkt = qt + 1;
  stage(0, 0);
  __syncthreads();
  int cur = 0;

  for (int kt = 0; kt < nkt; kt++){
    const int k0 = kt * 64;

    // K fragments for THIS tile from global (L2): issue before the prefetch
    // so the MFMA waitcnt leaves the staging DMAs in flight.
    bf16x8 kbuf[4][4];
    #pragma unroll
    for (int f = 0; f < 4; f++)
      #pragma unroll
      for (int t = 0; t < 4; t++)
        kbuf[f][t] = *(const bf16x8*)(Kl + (size_t)(k0 + f * 16) * QKVST + t * 32);

    if (kt + 1 < nkt) stage(cur ^ 1, kt + 1);   // V prefetch overlaps compute

    // QK^T: 16 MFMAs, flat/unconditional -> sc[f]; key = k0 + f*16 + ln
    f32x4 sc[4] = {};
    __builtin_amdgcn_s_setprio(1);
    #pragma unroll
    for (int f = 0; f < 4; f++)
      #pragma unroll
      for (int t = 0; t < 4; t++)
        sc[f] = __builtin_amdgcn_mfma_f32_16x16x32_bf16(qf[t], kbuf[f][t], sc[f], 0, 0, 0);
    __builtin_amdgcn_s_setprio(0);

    // causal mask (diag tile only) — log2-domain logits
    const bool diag = (kt == qt);
    if (diag){
      #pragma unroll
      for (int f = 0; f < 4; f++)
        #pragma unroll
        for (int r = 0; r < 4; r++)
          if (k0 + f * 16 + ln > qw + g * 4 + r) sc[f][r] = -1e30f;
    }
    // per-row tile max
    float mx[4];
    #pragma unroll
    for (int r = 0; r < 4; r++){
      float t = fmaxf(fmaxf(sc[0][r], sc[1][r]), fmaxf(sc[2][r], sc[3][r]));
      #pragma unroll
      for (int d = 1; d < 16; d <<= 1) t = fmaxf(t, __shfl_xor(t, d));
      mx[r] = t;
    }
    // defer-max: only rescale when some row grew past THR (log2 units)
    int ok = (mx[0] <= m_r[0] + RESCALE_THR2) & (mx[1] <= m_r[1] + RESCALE_THR2)
           & (mx[2] <= m_r[2] + RESCALE_THR2) & (mx[3] <= m_r[3] + RESCALE_THR2);
    if (!__all(ok)){
      float sf_[4];
      #pragma unroll
      for (int r = 0; r < 4; r++){
        float mn = fmaxf(m_r[r], mx[r]);
        sf_[r] = exp2f(m_r[r] - mn);
        m_r[r] = mn;
      }
      #pragma unroll
      for (int fn = 0; fn < 8; fn++)
        #pragma unroll
        for (int r = 0; r < 4; r++) O[fn][r] *= sf_[r];
      #pragma unroll
      for (int r = 0; r < 4; r++) L[r] *= sf_[r];
    }
    // P = exp2(s - m), store bf16 (swizzled) for PV A-frag
    u16* Pw = Ps[w];
    #pragma unroll
    for (int r = 0; r < 4; r++){
      const int row = g * 4 + r;
      #pragma unroll
      for (int f = 0; f < 4; f++){
        float p = exp2f(sc[f][r] - m_r[r]);
        Pw[row * 64 + ((f * 16 + ln) ^ ((row & 7) << 3))] = f2bf(p);
      }
    }
    // PV: P A-frag row = ln (wave-local LDS, in-order); l via register ones
    const u16* Vc = Vs[cur];
    bf16x8 pa0 = *(const bf16x8*)&Pw[ln * 64 + ((g * 8)      ^ ((ln & 7) << 3))];
    bf16x8 pa1 = *(const bf16x8*)&Pw[ln * 64 + ((32 + g * 8) ^ ((ln & 7) << 3))];
    __builtin_amdgcn_s_setprio(1);
    #pragma unroll
    for (int fn = 0; fn < 8; fn++){
      const int vr = fn * 16 + ln;
      bf16x8 v0 = *(const bf16x8*)&Vc[vr * 64 + ((g * 8)      ^ ((ln & 7) << 3))];
      bf16x8 v1 = *(const bf16x8*)&Vc[vr * 64 + ((32 + g * 8) ^ ((ln & 7) << 3))];
      O[fn] = __builtin_amdgcn_mfma_f32_16x16x32_bf16(pa0, v0, O[fn], 0, 0, 0);
      O[fn] = __builtin_amdgcn_mfma_f32_16x16x32_bf16(pa1, v1, O[fn], 0, 0, 0);
    }
    L = __builtin_amdgcn_mfma_f32_16x16x32_bf16(pa0, onesf, L, 0, 0, 0);
    L = __builtin_amdgcn_mfma_f32_16x16x32_bf16(pa1, onesf, L, 0, 0, 0);
    __builtin_amdgcn_s_setprio(0);

    __syncthreads();   // ONE barrier/tile: drains prefetch vmcnt + guards reuse
    cur ^= 1;
  }
  // l (incl. sink term via init) lives in L[r] of lanes ln==0
  #pragma unroll
  for (int r = 0; r < 4; r++){
    float l = __shfl(L[r], lane & 48);
    float osc = 1.f / l;
    #pragma unroll
    for (int fn = 0; fn < 8; fn++)
      AO[(size_t)(qw + g * 4 + r) * AOST + h * HD + fn * 16 + ln] = f2bf(O[fn][r] * osc);
  }
}

// ---------------- host-side launch ----------------
extern "C" void kernel_launch(void* const* d_in, const int* in_sizes, int n_in,
                              void* d_out, int out_size, void* d_ws, size_t ws_size,
                              hipStream_t stream){
  (void)in_sizes; (void)n_in; (void)out_size; (void)ws_size;
  const float* hs    = (const float*)d_in[0];
  const float* cosv  = (const float*)d_in[1];
  const float* sinv  = (const float*)d_in[2];
  /* d_in[3] attention_mask: pure causal triu(NEG,1) - implemented directly */
  const float* Wq    = (const float*)d_in[4];
  const float* Wk    = (const float*)d_in[5];
  const float* Wv    = (const float*)d_in[6];
  const float* Wo    = (const float*)d_in[7];
  const float* sinkb = (const float*)d_in[8];
  float* out = (float*)d_out;

  char* ws = (char*)d_ws;
  u16* XB    = (u16*)(ws);                  //  8,388,608  X bf16 [2048][2048]
  u16* WQKVB = (u16*)(ws + 8388608);        // 25,165,824  Wqkv bf16 [6144][2048]
  u16* WOB   = (u16*)(ws + 33554432);       // 16,777,216  Wo bf16 [2048][4096]
  u16* QKV   = (u16*)(ws + 50331648);       // 25,165,824  QKV bf16 [2048][6144]
  u16* VT    = (u16*)(ws + 75497472);       //  4,194,304  V^T bf16 [8][128][2048]
  u16* AO    = (u16*)(ws + 79691776);       // 16,777,216  attn out bf16 [2048][4096]

  // single fused convert: hs|Wq|Wk|Wv|Wo -> XB|WQKVB|WOB (contiguous in ws)
  cvt_all_kernel<<<24576, 256, 0, stream>>>((const f32x4*)hs, (const f32x4*)Wq,
                                            (const f32x4*)Wk, (const f32x4*)Wv,
                                            (const f32x4*)Wo, (u16x4*)ws);

  // fused QKV projection + RoPE + Q-scale(log2e) epilogue: [2048][6144]
  gemm_bt_kernel<1, 1, 128><<<dim3(48, 16), 256, 0, stream>>>(XB, WQKVB, QKV, 2048, 6144, 2048, cosv, sinv);

  // V transpose (V region carries no rope)
  vtrans_kernel<<<8192, 256, 0, stream>>>(QKV, VT);

  // attention: flat 1024-block grid (64 q-rows/block), XCD-aligned kvh
  attn_kernel<<<dim3(1024), 256, 0, stream>>>(QKV, VT, sinkb, AO);

  // output projection (f32 out): BN=64 -> 512 blocks (2/CU rolling)
  gemm_bt_kernel<0, 0, 64><<<dim3(32, 16), 256, 0, stream>>>(AO, WOB, out, 2048, 2048, 4096, nullptr, nullptr);
}

// Round 11
// 239.177 us; speedup vs baseline: 1.3772x; 1.3772x over previous
//
#include <hip/hip_runtime.h>

typedef unsigned short u16;
typedef unsigned int   u32;
typedef __bf16  bf16x8 __attribute__((ext_vector_type(8)));
typedef float   f32x4  __attribute__((ext_vector_type(4)));
typedef float   f32x16 __attribute__((ext_vector_type(16)));
typedef u16     u16x4  __attribute__((ext_vector_type(4)));
typedef u16     u16x8  __attribute__((ext_vector_type(8)));
typedef u32     u32x4  __attribute__((ext_vector_type(4)));

#define S_LEN 2048
#define NH 32
#define NKVH 8
#define HD 128
#define QKVST 6144          /* packed QKV row stride  */
#define AOST  4096          /* attn-out row stride    */
#define ATT_SCALE 0.08838834764831845f
#define LOG2E 1.4426950408889634f
#define QSC2 (ATT_SCALE * LOG2E)
#define RESCALE_THR2 11.5f

__device__ __forceinline__ u16 f2bf(float f){
  u32 u = __builtin_bit_cast(u32, f);
  u += 0x7FFFu + ((u >> 16) & 1u);
  return (u16)(u >> 16);
}
__device__ __forceinline__ u32 cvtpk(float lo, float hi){
  u32 d;
  asm("v_cvt_pk_bf16_f32 %0, %1, %2" : "=v"(d) : "v"(lo), "v"(hi));
  return d;
}
// async global->LDS, 16B per lane. Dest must be wave-uniform base + lane*16.
__device__ __forceinline__ void gload_lds16(const u16* g, u16* l){
  __builtin_amdgcn_global_load_lds(
      (const __attribute__((address_space(1))) void*)g,
      (__attribute__((address_space(3))) void*)l, 16, 0, 0);
}

// ------------- fused f32 -> bf16 convert of ALL inputs (one launch) --------
__global__ void cvt_all_kernel(const f32x4* __restrict__ hs, const f32x4* __restrict__ wq,
                               const f32x4* __restrict__ wk, const f32x4* __restrict__ wv,
                               const f32x4* __restrict__ wo, u16x4* __restrict__ out){
  int i = blockIdx.x * 256 + threadIdx.x;          // 0 .. 6291455
  const f32x4* src; int off;
  if      (i < 1048576){ src = hs; off = i; }
  else if (i < 3145728){ src = wq; off = i - 1048576; }
  else if (i < 3670016){ src = wk; off = i - 3145728; }
  else if (i < 4194304){ src = wv; off = i - 3670016; }
  else                 { src = wo; off = i - 4194304; }
  f32x4 v = src[off];
  u16x4 o;
  o[0] = f2bf(v[0]); o[1] = f2bf(v[1]); o[2] = f2bf(v[2]); o[3] = f2bf(v[3]);
  out[i] = o;
}

// ---------------- GEMM: C[M][N] = X[M][K] @ W[N][K]^T (bf16 in, f32 acc) ----
// (unchanged from R9: 128xBN tile, BK=64, dbuf prefetch, fused RoPE+Qscale)
template<int OUT_BF16, int ROPE, int BN>
__global__ __launch_bounds__(256, 2)
void gemm_bt_kernel(const u16* __restrict__ X, const u16* __restrict__ W,
                    void* __restrict__ Cv, int M, int N, int K,
                    const float* __restrict__ cosv, const float* __restrict__ sinv){
  __shared__ __align__(16) u16 As[2][2][128 * 32];
  __shared__ __align__(16) u16 Bs[2][2][BN * 32];
  const int NJ = BN / 32;
  const int m0 = blockIdx.y * 128, n0 = blockIdx.x * BN;
  const int tid = threadIdx.x;
  const int wave = tid >> 6, lane = tid & 63;
  const int wm = wave >> 1, wn = wave & 1;
  const int g = lane >> 4, ln = lane & 15;
  const int r0 = tid >> 2;
  const int cc = (tid & 3) * 8;
  f32x4 acc[4][NJ] = {};
  const u16* xa0 = X + (size_t)(m0 + r0) * K + cc;
  const u16* xa1 = X + (size_t)(m0 + r0 + 64) * K + cc;
  const u16* wb0 = W + (size_t)(n0 + r0) * K + cc;
  const u16* wb1 = W + (size_t)(n0 + r0 + (BN == 128 ? 64 : 0)) * K + cc;

  auto stage = [&](int buf, int k0){
    #pragma unroll
    for (int s = 0; s < 2; s++){
      const int kc = k0 + s * 32;
      gload_lds16(xa0 + kc, &As[buf][s][tid * 8]);
      gload_lds16(xa1 + kc, &As[buf][s][2048 + tid * 8]);
      gload_lds16(wb0 + kc, &Bs[buf][s][tid * 8]);
      if (BN == 128) gload_lds16(wb1 + kc, &Bs[buf][s][2048 + tid * 8]);
    }
  };

  stage(0, 0);
  __syncthreads();
  int cur = 0;
  for (int k0 = 0; k0 < K; k0 += 64){
    if (k0 + 64 < K) stage(cur ^ 1, k0 + 64);
    #pragma unroll
    for (int s = 0; s < 2; s++){
      bf16x8 a[4], b[NJ];
      #pragma unroll
      for (int f = 0; f < 4; f++) a[f] = *(const bf16x8*)&As[cur][s][(wm * 64 + f * 16 + ln) * 32 + g * 8];
      #pragma unroll
      for (int f = 0; f < NJ; f++) b[f] = *(const bf16x8*)&Bs[cur][s][(wn * (BN / 2) + f * 16 + ln) * 32 + g * 8];
      __builtin_amdgcn_s_setprio(1);
      #pragma unroll
      for (int i = 0; i < 4; i++)
        #pragma unroll
        for (int j = 0; j < NJ; j++)
          acc[i][j] = __builtin_amdgcn_mfma_f32_16x16x32_bf16(a[i], b[j], acc[i][j], 0, 0, 0);
      __builtin_amdgcn_s_setprio(0);
    }
    __syncthreads();
    cur ^= 1;
  }
  if (ROPE && BN == 128){
    if (wn == 0 && n0 < 5120){
      #pragma unroll
      for (int i = 0; i < 4; i++)
        #pragma unroll
        for (int r = 0; r < 4; r++){
          const int row = m0 + wm * 64 + i * 16 + g * 4 + r;
          #pragma unroll
          for (int j = 0; j < 2; j++){
            const int d = j * 16 + ln;
            float c  = cosv[row * 64 + d];
            float sn = sinv[row * 64 + d];
            float x0 = acc[i][j][r], x1 = acc[i][j + 2][r];
            acc[i][j][r]     = x0 * c - x1 * sn;
            acc[i][j + 2][r] = x1 * c + x0 * sn;
          }
        }
    }
    if (n0 < 4096){
      #pragma unroll
      for (int i = 0; i < 4; i++)
        #pragma unroll
        for (int j = 0; j < 4; j++)
          #pragma unroll
          for (int r = 0; r < 4; r++) acc[i][j][r] *= QSC2;
    }
  }
  #pragma unroll
  for (int i = 0; i < 4; i++)
    #pragma unroll
    for (int j = 0; j < NJ; j++)
      #pragma unroll
      for (int r = 0; r < 4; r++){
        int row = m0 + wm * 64 + i * 16 + g * 4 + r;
        int col = n0 + wn * (BN / 2) + j * 16 + ln;
        if (OUT_BF16) ((u16*)Cv)[(size_t)row * N + col] = f2bf(acc[i][j][r]);
        else          ((float*)Cv)[(size_t)row * N + col] = acc[i][j][r];
      }
}

// ---------------- V transpose: VT[kvh][vd][s] from packed QKV -------------
__global__ void vtrans_kernel(const u16* __restrict__ QKV, u16* __restrict__ VT){
  int idx = blockIdx.x * 256 + threadIdx.x;
  if (idx >= NKVH * HD * S_LEN) return;
  int s   = idx & (S_LEN - 1);
  int vd  = (idx >> 11) & (HD - 1);
  int kvh = idx >> 18;
  VT[idx] = QKV[(size_t)s * QKVST + 5120 + kvh * HD + vd];
}

// ---------------- causal flash attention, swapped-operand 32x32 MFMA -------
// 512 blocks, 4 waves x 32 q-rows (128q/block), KVBLK=64, K/V dbuf = 64KB
// (2 blocks/CU, 8 waves/CU). Slot order pairs qt {15-s, s} so the 2 blocks
// sharing a CU (b, b+256 under round-robin) sum to a uniform 34 tiles.
// QK = mfma(A=K, B=Q): scores col=q=lane&31, keys in regs -> in-lane softmax
// (no P LDS round-trip, no shfl chains). P->bf16 via cvt_pk + permlane32_swap
// (T12). PV = mfma(A=V, B=P): O col=q -> in-lane rescale + 1/l.
// LDS: 512B rows (K: key-pair, V: vd-quad) with XOR swizzle -> 2-way (free).
// Per wave-tile (32q x 64k): 16 K-reads + 16 V-reads + 32 MFMA. Epilogue
// transposes O via the dead K buffer for coalesced AO stores.
__global__ __launch_bounds__(256, 2)
void attn_kernel(const u16* __restrict__ QKV, const u16* __restrict__ VT,
                 const float* __restrict__ sinkb, u16* __restrict__ AO){
  __shared__ __align__(16) u16 Ks[2][32 * 256];   // 64 keys: key-pair rows, 512B
  __shared__ __align__(16) u16 Vs[2][32 * 256];   // 128 vd: vd-quad rows, 512B
  const int b    = blockIdx.x;
  const int kvh  = b & 7;                  // XCD-aligned kv-head
  const int head = kvh * 4 + ((b >> 3) & 3);
  const int slot = b >> 5;                 // 0..15
  const int qt   = (slot < 8) ? (15 - slot) : (slot - 8);  // CU-pair balance
  const int tid  = threadIdx.x;
  const int w    = tid >> 6;               // q-group 0..3
  const int lane = tid & 63;
  const int l31  = lane & 31, hi = lane >> 5;
  const int q0   = qt * 128;
  const int qw   = q0 + w * 32;            // wave's 32 q-rows

  const u16* Kbase = QKV + 4096 + kvh * HD;           // + row*QKVST
  const u16* Vbase = VT + (size_t)kvh * HD * S_LEN;   // + vd*S_LEN + key

  // stage tile kt (64 keys): K 1024 chunks + V 1024 chunks, swizzled source
  auto stage = [&](int buf, int kt){
    const int k0 = kt * 64;
    #pragma unroll
    for (int p = 0; p < 4; p++){
      int idx = p * 256 + tid;             // K: row r(32) x chunk c(32)
      int r = idx >> 5, c = idx & 31;
      int cs = c ^ r;                      // r == r&31
      int key = r * 2 + (cs >> 4), d8 = (cs & 15) * 8;
      gload_lds16(Kbase + (size_t)(k0 + key) * QKVST + d8, &Ks[buf][idx * 8]);
    }
    #pragma unroll
    for (int p = 0; p < 4; p++){
      int idx = p * 256 + tid;             // V: row r(32) x chunk c(32)
      int r = idx >> 5, c = idx & 31;
      int cs = c ^ r;
      int vd = r * 4 + (cs >> 3), k8 = (cs & 7) * 8;
      gload_lds16(Vbase + (size_t)vd * S_LEN + k0 + k8, &Vs[buf][idx * 8]);
    }
  };

  // Q as B-frags (pre-scaled by ATT_SCALE*log2e): lane holds col q = l31,
  // k = t*16 + hi*8 + j
  bf16x8 qB[8];
  const u16* qrow = QKV + (size_t)(qw + l31) * QKVST + head * HD;
  #pragma unroll
  for (int t = 0; t < 8; t++) qB[t] = *(const bf16x8*)(qrow + t * 16 + hi * 8);

  // sink folded into init: m = sink*log2e; L starts at 1 (counted once, hi=0)
  float m  = sinkb[head] * LOG2E;
  float Ll = (hi == 0) ? 1.f : 0.f;
  f32x16 O[4] = {};                        // nsub: vd = nsub*32 + rowpat(r,hi)

  const int nkt = 2 * qt + 2;
  stage(0, 0);
  __syncthreads();
  int cur = 0;

  for (int kt = 0; kt < nkt; kt++){
    const int k0 = kt * 64;
    if (kt + 1 < nkt) stage(cur ^ 1, kt + 1);

    if (k0 < qw + 32){                     // wave-uniform skip of masked tiles
      const u16* Kc = Ks[cur];
      const u16* Vc = Vs[cur];
      // QK^T: sc[s] = mfma(K_sub_s, Q); D[key(regs)][q=l31]
      f32x16 sc0 = {}, sc1 = {};
      const int krow0 = (l31 >> 1);              // s=0 row; s=1: +16
      const int kc0   = ((l31 & 1) << 4) | hi;   // + 2t
      __builtin_amdgcn_s_setprio(1);
      #pragma unroll
      for (int t = 0; t < 8; t++){
        bf16x8 ka0 = *(const bf16x8*)&Kc[krow0 * 256 + ((kc0 + 2 * t) ^ krow0) * 8];
        bf16x8 ka1 = *(const bf16x8*)&Kc[(16 + krow0) * 256 + ((kc0 + 2 * t) ^ (16 + krow0)) * 8];
        sc0 = __builtin_amdgcn_mfma_f32_32x32x16_bf16(ka0, qB[t], sc0, 0, 0, 0);
        sc1 = __builtin_amdgcn_mfma_f32_32x32x16_bf16(ka1, qB[t], sc1, 0, 0, 0);
      }
      __builtin_amdgcn_s_setprio(0);

      // causal mask (in-lane: q = l31, key = reg pattern)
      if (k0 + 63 > qw){
        const int qg = qw + l31;
        #pragma unroll
        for (int r = 0; r < 16; r++){
          int keyr = k0 + (r & 3) + 8 * (r >> 2) + 4 * hi;
          if (keyr      > qg) sc0[r] = -1e30f;
          if (keyr + 32 > qg) sc1[r] = -1e30f;
        }
      }
      // tile max (in-lane 31 fmax + partner swap)
      float mx = sc0[0];
      #pragma unroll
      for (int r = 1; r < 16; r++) mx = fmaxf(mx, sc0[r]);
      #pragma unroll
      for (int r = 0; r < 16; r++) mx = fmaxf(mx, sc1[r]);
      mx = fmaxf(mx, __shfl_xor(mx, 32));
      // defer-max rescale (all per-lane: q = l31)
      if (!__all(mx <= m + RESCALE_THR2)){
        float mn = fmaxf(m, mx);
        float sf = exp2f(m - mn);
        m = mn;
        #pragma unroll
        for (int n = 0; n < 4; n++)
          #pragma unroll
          for (int r = 0; r < 16; r++) O[n][r] *= sf;
        Ll *= sf;
      }
      // P = exp2(sc - m); accumulate l in-lane
      float p0[16], p1[16];
      #pragma unroll
      for (int r = 0; r < 16; r++){ p0[r] = exp2f(sc0[r] - m); Ll += p0[r]; }
      #pragma unroll
      for (int r = 0; r < 16; r++){ p1[r] = exp2f(sc1[r] - m); Ll += p1[r]; }

      // pack P -> bf16 A/B-frags via cvt_pk + permlane32_swap (T12), then PV
      __builtin_amdgcn_s_setprio(1);
      #pragma unroll
      for (int c = 0; c < 4; c++){
        const float* ps = (c & 2) ? p1 : p0;
        const int bb = (c & 1) * 8;
        u32 wa = cvtpk(ps[bb + 0], ps[bb + 1]);
        u32 wb = cvtpk(ps[bb + 2], ps[bb + 3]);
        u32 wc = cvtpk(ps[bb + 4], ps[bb + 5]);
        u32 wd = cvtpk(ps[bb + 6], ps[bb + 7]);
        asm("v_permlane32_swap_b32 %0, %1" : "+v"(wa), "+v"(wc));
        asm("v_permlane32_swap_b32 %0, %1" : "+v"(wb), "+v"(wd));
        u32x4 wv_; wv_[0] = wa; wv_[1] = wb; wv_[2] = wc; wv_[3] = wd;
        bf16x8 pf = __builtin_bit_cast(bf16x8, wv_);
        // PV: O[n] = mfma(A=V[vd=n*32+l31][keys c*16+hi*8..], B=P)
        #pragma unroll
        for (int n = 0; n < 4; n++){
          const int vrow = n * 8 + (l31 >> 2);
          const int vcc  = ((l31 & 3) << 3) | (c << 1) | hi;
          bf16x8 va = *(const bf16x8*)&Vc[vrow * 256 + (vcc ^ vrow) * 8];
          O[n] = __builtin_amdgcn_mfma_f32_32x32x16_bf16(va, pf, O[n], 0, 0, 0);
        }
      }
      __builtin_amdgcn_s_setprio(0);
    }
    __syncthreads();                       // drains prefetch vmcnt + reuse guard
    cur ^= 1;
  }

  // epilogue: in-lane 1/l; transpose O via dead K buffer for coalesced stores
  float l = Ll + __shfl_xor(Ll, 32);
  float inv = 1.f / l;
  u16* arena = &Ks[0][0];                  // 32KB: wave w gets 8KB (32q x 256B)
  #pragma unroll
  for (int n = 0; n < 4; n++)
    #pragma unroll
    for (int r = 0; r < 16; r++){
      int vd = n * 32 + (r & 3) + 8 * (r >> 2) + 4 * hi;
      int ch = (vd >> 3) ^ (l31 & 15);
      arena[w * 4096 + l31 * 128 + ch * 8 + (vd & 7)] = f2bf(O[n][r] * inv);
    }
  __syncthreads();
  #pragma unroll
  for (int p = 0; p < 8; p++){
    int idx = p * 256 + tid;               // 2048 chunks: row(128) x c(16)
    int row = idx >> 4, c = idx & 15;
    u16x8 v = *(const u16x8*)&arena[row * 128 + ((c ^ (row & 15)) * 8)];
    *(u16x8*)&AO[(size_t)(q0 + row) * AOST + head * HD + c * 8] = v;
  }
}

// ---------------- host-side launch ----------------
extern "C" void kernel_launch(void* const* d_in, const int* in_sizes, int n_in,
                              void* d_out, int out_size, void* d_ws, size_t ws_size,
                              hipStream_t stream){
  (void)in_sizes; (void)n_in; (void)out_size; (void)ws_size;
  const float* hs    = (const float*)d_in[0];
  const float* cosv  = (const float*)d_in[1];
  const float* sinv  = (const float*)d_in[2];
  /* d_in[3] attention_mask: pure causal triu(NEG,1) - implemented directly */
  const float* Wq    = (const float*)d_in[4];
  const float* Wk    = (const float*)d_in[5];
  const float* Wv    = (const float*)d_in[6];
  const float* Wo    = (const float*)d_in[7];
  const float* sinkb = (const float*)d_in[8];
  float* out = (float*)d_out;

  char* ws = (char*)d_ws;
  u16* XB    = (u16*)(ws);                  //  8,388,608  X bf16 [2048][2048]
  u16* WQKVB = (u16*)(ws + 8388608);        // 25,165,824  Wqkv bf16 [6144][2048]
  u16* WOB   = (u16*)(ws + 33554432);       // 16,777,216  Wo bf16 [2048][4096]
  u16* QKV   = (u16*)(ws + 50331648);       // 25,165,824  QKV bf16 [2048][6144]
  u16* VT    = (u16*)(ws + 75497472);       //  4,194,304  V^T bf16 [8][128][2048]
  u16* AO    = (u16*)(ws + 79691776);       // 16,777,216  attn out bf16 [2048][4096]

  cvt_all_kernel<<<24576, 256, 0, stream>>>((const f32x4*)hs, (const f32x4*)Wq,
                                            (const f32x4*)Wk, (const f32x4*)Wv,
                                            (const f32x4*)Wo, (u16x4*)ws);

  gemm_bt_kernel<1, 1, 128><<<dim3(48, 16), 256, 0, stream>>>(XB, WQKVB, QKV, 2048, 6144, 2048, cosv, sinv);

  vtrans_kernel<<<8192, 256, 0, stream>>>(QKV, VT);

  // attention: 512 blocks (128 q-rows each), CU-pair-balanced qt order
  attn_kernel<<<dim3(512), 256, 0, stream>>>(QKV, VT, sinkb, AO);

  gemm_bt_kernel<0, 0, 64><<<dim3(32, 16), 256, 0, stream>>>(AO, WOB, out, 2048, 2048, 4096, nullptr, nullptr);
}

// Round 12
// 239.068 us; speedup vs baseline: 1.3778x; 1.0005x over previous
//
#include <hip/hip_runtime.h>

typedef unsigned short u16;
typedef unsigned int   u32;
typedef __bf16  bf16x8 __attribute__((ext_vector_type(8)));
typedef float   f32x4  __attribute__((ext_vector_type(4)));
typedef float   f32x16 __attribute__((ext_vector_type(16)));
typedef u16     u16x4  __attribute__((ext_vector_type(4)));
typedef u16     u16x8  __attribute__((ext_vector_type(8)));
typedef u32     u32x4  __attribute__((ext_vector_type(4)));

#define S_LEN 2048
#define NH 32
#define NKVH 8
#define HD 128
#define QKVST 6144          /* packed QKV row stride  */
#define AOST  4096          /* attn-out row stride    */
#define ATT_SCALE 0.08838834764831845f
#define LOG2E 1.4426950408889634f
#define QSC2 (ATT_SCALE * LOG2E)
#define RESCALE_THR2 11.5f

__device__ __forceinline__ u16 f2bf(float f){
  u32 u = __builtin_bit_cast(u32, f);
  u += 0x7FFFu + ((u >> 16) & 1u);
  return (u16)(u >> 16);
}
__device__ __forceinline__ u32 cvtpk(float lo, float hi){
  u32 d;
  asm("v_cvt_pk_bf16_f32 %0, %1, %2" : "=v"(d) : "v"(lo), "v"(hi));
  return d;
}
// async global->LDS, 16B per lane. Dest must be wave-uniform base + lane*16.
__device__ __forceinline__ void gload_lds16(const u16* g, u16* l){
  __builtin_amdgcn_global_load_lds(
      (const __attribute__((address_space(1))) void*)g,
      (__attribute__((address_space(3))) void*)l, 16, 0, 0);
}

// ------------- fused f32 -> bf16 convert of ALL inputs (one launch) --------
__global__ void cvt_all_kernel(const f32x4* __restrict__ hs, const f32x4* __restrict__ wq,
                               const f32x4* __restrict__ wk, const f32x4* __restrict__ wv,
                               const f32x4* __restrict__ wo, u16x4* __restrict__ out){
  int i = blockIdx.x * 256 + threadIdx.x;          // 0 .. 6291455
  const f32x4* src; int off;
  if      (i < 1048576){ src = hs; off = i; }
  else if (i < 3145728){ src = wq; off = i - 1048576; }
  else if (i < 3670016){ src = wk; off = i - 3145728; }
  else if (i < 4194304){ src = wv; off = i - 3670016; }
  else                 { src = wo; off = i - 4194304; }
  f32x4 v = src[off];
  u16x4 o;
  o[0] = f2bf(v[0]); o[1] = f2bf(v[1]); o[2] = f2bf(v[2]); o[3] = f2bf(v[3]);
  out[i] = o;
}

// ---------------- GEMM: C[M][N] = X[M][K] @ W[N][K]^T (bf16 in, f32 acc) ----
// BM x BN tile, BK=64 (2x 32-sub-tiles), dbuf prefetch, 4 waves (2x2).
// QKV: BM=64, BN=128 -> grid 48x32 = 1536 = 3 EXACT rounds of 512 co-resident
// blocks (the 128x128 grid was 768 = 1.5 rounds: tail ran at half occupancy,
// measured 614 TF vs O-proj's ~818 at exact rounds). BN=128 keeps the fused
// RoPE pairing (acc j <-> j+2 within wn==0) intact.
template<int OUT_BF16, int ROPE, int BM, int BN>
__global__ __launch_bounds__(256, 2)
void gemm_bt_kernel(const u16* __restrict__ X, const u16* __restrict__ W,
                    void* __restrict__ Cv, int M, int N, int K,
                    const float* __restrict__ cosv, const float* __restrict__ sinv){
  __shared__ __align__(16) u16 As[2][2][BM * 32];
  __shared__ __align__(16) u16 Bs[2][2][BN * 32];
  const int MI = BM / 32, NJ = BN / 32;   // frags per wave (wave-tile BM/2 x BN/2)
  const int m0 = blockIdx.y * BM, n0 = blockIdx.x * BN;
  const int tid = threadIdx.x;
  const int wave = tid >> 6, lane = tid & 63;
  const int wm = wave >> 1, wn = wave & 1;
  const int g = lane >> 4, ln = lane & 15;
  const int r0 = tid >> 2;            // rows 0..63 (tid*16B == linear LDS dest)
  const int cc = (tid & 3) * 8;       // bf16 col within sub-tile BK=32
  f32x4 acc[MI][NJ] = {};
  const u16* xa0 = X + (size_t)(m0 + r0) * K + cc;
  const u16* xa1 = X + (size_t)(m0 + r0 + 64) * K + cc;   // BM==128 only
  const u16* wb0 = W + (size_t)(n0 + r0) * K + cc;
  const u16* wb1 = W + (size_t)(n0 + r0 + 64) * K + cc;   // BN==128 only

  auto stage = [&](int buf, int k0){
    #pragma unroll
    for (int s = 0; s < 2; s++){
      const int kc = k0 + s * 32;
      gload_lds16(xa0 + kc, &As[buf][s][tid * 8]);
      if (BM == 128) gload_lds16(xa1 + kc, &As[buf][s][2048 + tid * 8]);
      gload_lds16(wb0 + kc, &Bs[buf][s][tid * 8]);
      if (BN == 128) gload_lds16(wb1 + kc, &Bs[buf][s][2048 + tid * 8]);
    }
  };

  stage(0, 0);
  __syncthreads();                       // implicit vmcnt(0): tile 0 ready
  int cur = 0;
  for (int k0 = 0; k0 < K; k0 += 64){
    if (k0 + 64 < K) stage(cur ^ 1, k0 + 64);   // prefetch overlaps compute
    #pragma unroll
    for (int s = 0; s < 2; s++){
      bf16x8 a[MI], b[NJ];
      #pragma unroll
      for (int f = 0; f < MI; f++) a[f] = *(const bf16x8*)&As[cur][s][(wm * (BM / 2) + f * 16 + ln) * 32 + g * 8];
      #pragma unroll
      for (int f = 0; f < NJ; f++) b[f] = *(const bf16x8*)&Bs[cur][s][(wn * (BN / 2) + f * 16 + ln) * 32 + g * 8];
      __builtin_amdgcn_s_setprio(1);
      #pragma unroll
      for (int i = 0; i < MI; i++)
        #pragma unroll
        for (int j = 0; j < NJ; j++)
          acc[i][j] = __builtin_amdgcn_mfma_f32_16x16x32_bf16(a[i], b[j], acc[i][j], 0, 0, 0);
      __builtin_amdgcn_s_setprio(0);
    }
    __syncthreads();   // ONE barrier/tile: drains prefetch vmcnt + guards reuse
    cur ^= 1;
  }
  if (ROPE && BN == 128){
    // fused partial RoPE: Q/K column blocks (n0<5120), first-half dims (wn==0)
    if (wn == 0 && n0 < 5120){
      #pragma unroll
      for (int i = 0; i < MI; i++)
        #pragma unroll
        for (int r = 0; r < 4; r++){
          const int row = m0 + wm * (BM / 2) + i * 16 + g * 4 + r;
          #pragma unroll
          for (int j = 0; j < 2; j++){
            const int d = j * 16 + ln;               // 0..31, partner d+32
            float c  = cosv[row * 64 + d];
            float sn = sinv[row * 64 + d];
            float x0 = acc[i][j][r], x1 = acc[i][j + 2][r];
            acc[i][j][r]     = x0 * c - x1 * sn;
            acc[i][j + 2][r] = x1 * c + x0 * sn;
          }
        }
    }
    // fold attention scale * log2(e) into Q: attn works in exp2 domain
    if (n0 < 4096){
      #pragma unroll
      for (int i = 0; i < MI; i++)
        #pragma unroll
        for (int j = 0; j < NJ; j++)
          #pragma unroll
          for (int r = 0; r < 4; r++) acc[i][j][r] *= QSC2;
    }
  }
  // epilogue: C/D layout col = lane&15, row = (lane>>4)*4 + reg  [m89]
  #pragma unroll
  for (int i = 0; i < MI; i++)
    #pragma unroll
    for (int j = 0; j < NJ; j++)
      #pragma unroll
      for (int r = 0; r < 4; r++){
        int row = m0 + wm * (BM / 2) + i * 16 + g * 4 + r;
        int col = n0 + wn * (BN / 2) + j * 16 + ln;
        if (OUT_BF16) ((u16*)Cv)[(size_t)row * N + col] = f2bf(acc[i][j][r]);
        else          ((float*)Cv)[(size_t)row * N + col] = acc[i][j][r];
      }
}

// ---------------- V transpose: VT[kvh][vd][s] from packed QKV -------------
__global__ void vtrans_kernel(const u16* __restrict__ QKV, u16* __restrict__ VT){
  int idx = blockIdx.x * 256 + threadIdx.x;
  if (idx >= NKVH * HD * S_LEN) return;
  int s   = idx & (S_LEN - 1);
  int vd  = (idx >> 11) & (HD - 1);
  int kvh = idx >> 18;
  VT[idx] = QKV[(size_t)s * QKVST + 5120 + kvh * HD + vd];
}

// ---------------- causal flash attention, swapped-operand 32x32 MFMA -------
// (unchanged from R11 — landed: 512 blocks, 4 waves x 32 q, in-lane softmax)
__global__ __launch_bounds__(256, 2)
void attn_kernel(const u16* __restrict__ QKV, const u16* __restrict__ VT,
                 const float* __restrict__ sinkb, u16* __restrict__ AO){
  __shared__ __align__(16) u16 Ks[2][32 * 256];   // 64 keys: key-pair rows, 512B
  __shared__ __align__(16) u16 Vs[2][32 * 256];   // 128 vd: vd-quad rows, 512B
  const int b    = blockIdx.x;
  const int kvh  = b & 7;                  // XCD-aligned kv-head
  const int head = kvh * 4 + ((b >> 3) & 3);
  const int slot = b >> 5;                 // 0..15
  const int qt   = (slot < 8) ? (15 - slot) : (slot - 8);  // CU-pair balance
  const int tid  = threadIdx.x;
  const int w    = tid >> 6;               // q-group 0..3
  const int lane = tid & 63;
  const int l31  = lane & 31, hi = lane >> 5;
  const int q0   = qt * 128;
  const int qw   = q0 + w * 32;            // wave's 32 q-rows

  const u16* Kbase = QKV + 4096 + kvh * HD;           // + row*QKVST
  const u16* Vbase = VT + (size_t)kvh * HD * S_LEN;   // + vd*S_LEN + key

  auto stage = [&](int buf, int kt){
    const int k0 = kt * 64;
    #pragma unroll
    for (int p = 0; p < 4; p++){
      int idx = p * 256 + tid;             // K: row r(32) x chunk c(32)
      int r = idx >> 5, c = idx & 31;
      int cs = c ^ r;
      int key = r * 2 + (cs >> 4), d8 = (cs & 15) * 8;
      gload_lds16(Kbase + (size_t)(k0 + key) * QKVST + d8, &Ks[buf][idx * 8]);
    }
    #pragma unroll
    for (int p = 0; p < 4; p++){
      int idx = p * 256 + tid;             // V: row r(32) x chunk c(32)
      int r = idx >> 5, c = idx & 31;
      int cs = c ^ r;
      int vd = r * 4 + (cs >> 3), k8 = (cs & 7) * 8;
      gload_lds16(Vbase + (size_t)vd * S_LEN + k0 + k8, &Vs[buf][idx * 8]);
    }
  };

  // Q as B-frags (pre-scaled by ATT_SCALE*log2e): lane holds col q = l31
  bf16x8 qB[8];
  const u16* qrow = QKV + (size_t)(qw + l31) * QKVST + head * HD;
  #pragma unroll
  for (int t = 0; t < 8; t++) qB[t] = *(const bf16x8*)(qrow + t * 16 + hi * 8);

  // sink folded into init: m = sink*log2e; L starts at 1 (counted once, hi=0)
  float m  = sinkb[head] * LOG2E;
  float Ll = (hi == 0) ? 1.f : 0.f;
  f32x16 O[4] = {};

  const int nkt = 2 * qt + 2;
  stage(0, 0);
  __syncthreads();
  int cur = 0;

  for (int kt = 0; kt < nkt; kt++){
    const int k0 = kt * 64;
    if (kt + 1 < nkt) stage(cur ^ 1, kt + 1);

    if (k0 < qw + 32){                     // wave-uniform skip of masked tiles
      const u16* Kc = Ks[cur];
      const u16* Vc = Vs[cur];
      f32x16 sc0 = {}, sc1 = {};
      const int krow0 = (l31 >> 1);
      const int kc0   = ((l31 & 1) << 4) | hi;
      __builtin_amdgcn_s_setprio(1);
      #pragma unroll
      for (int t = 0; t < 8; t++){
        bf16x8 ka0 = *(const bf16x8*)&Kc[krow0 * 256 + ((kc0 + 2 * t) ^ krow0) * 8];
        bf16x8 ka1 = *(const bf16x8*)&Kc[(16 + krow0) * 256 + ((kc0 + 2 * t) ^ (16 + krow0)) * 8];
        sc0 = __builtin_amdgcn_mfma_f32_32x32x16_bf16(ka0, qB[t], sc0, 0, 0, 0);
        sc1 = __builtin_amdgcn_mfma_f32_32x32x16_bf16(ka1, qB[t], sc1, 0, 0, 0);
      }
      __builtin_amdgcn_s_setprio(0);

      if (k0 + 63 > qw){
        const int qg = qw + l31;
        #pragma unroll
        for (int r = 0; r < 16; r++){
          int keyr = k0 + (r & 3) + 8 * (r >> 2) + 4 * hi;
          if (keyr      > qg) sc0[r] = -1e30f;
          if (keyr + 32 > qg) sc1[r] = -1e30f;
        }
      }
      float mx = sc0[0];
      #pragma unroll
      for (int r = 1; r < 16; r++) mx = fmaxf(mx, sc0[r]);
      #pragma unroll
      for (int r = 0; r < 16; r++) mx = fmaxf(mx, sc1[r]);
      mx = fmaxf(mx, __shfl_xor(mx, 32));
      if (!__all(mx <= m + RESCALE_THR2)){
        float mn = fmaxf(m, mx);
        float sf = exp2f(m - mn);
        m = mn;
        #pragma unroll
        for (int n = 0; n < 4; n++)
          #pragma unroll
          for (int r = 0; r < 16; r++) O[n][r] *= sf;
        Ll *= sf;
      }
      float p0[16], p1[16];
      #pragma unroll
      for (int r = 0; r < 16; r++){ p0[r] = exp2f(sc0[r] - m); Ll += p0[r]; }
      #pragma unroll
      for (int r = 0; r < 16; r++){ p1[r] = exp2f(sc1[r] - m); Ll += p1[r]; }

      __builtin_amdgcn_s_setprio(1);
      #pragma unroll
      for (int c = 0; c < 4; c++){
        const float* ps = (c & 2) ? p1 : p0;
        const int bb = (c & 1) * 8;
        u32 wa = cvtpk(ps[bb + 0], ps[bb + 1]);
        u32 wb = cvtpk(ps[bb + 2], ps[bb + 3]);
        u32 wc = cvtpk(ps[bb + 4], ps[bb + 5]);
        u32 wd = cvtpk(ps[bb + 6], ps[bb + 7]);
        asm("v_permlane32_swap_b32 %0, %1" : "+v"(wa), "+v"(wc));
        asm("v_permlane32_swap_b32 %0, %1" : "+v"(wb), "+v"(wd));
        u32x4 wv_; wv_[0] = wa; wv_[1] = wb; wv_[2] = wc; wv_[3] = wd;
        bf16x8 pf = __builtin_bit_cast(bf16x8, wv_);
        #pragma unroll
        for (int n = 0; n < 4; n++){
          const int vrow = n * 8 + (l31 >> 2);
          const int vcc  = ((l31 & 3) << 3) | (c << 1) | hi;
          bf16x8 va = *(const bf16x8*)&Vc[vrow * 256 + (vcc ^ vrow) * 8];
          O[n] = __builtin_amdgcn_mfma_f32_32x32x16_bf16(va, pf, O[n], 0, 0, 0);
        }
      }
      __builtin_amdgcn_s_setprio(0);
    }
    __syncthreads();
    cur ^= 1;
  }

  // epilogue: in-lane 1/l; transpose O via dead K buffer for coalesced stores
  float l = Ll + __shfl_xor(Ll, 32);
  float inv = 1.f / l;
  u16* arena = &Ks[0][0];                  // 32KB: wave w gets 8KB (32q x 256B)
  #pragma unroll
  for (int n = 0; n < 4; n++)
    #pragma unroll
    for (int r = 0; r < 16; r++){
      int vd = n * 32 + (r & 3) + 8 * (r >> 2) + 4 * hi;
      int ch = (vd >> 3) ^ (l31 & 15);
      arena[w * 4096 + l31 * 128 + ch * 8 + (vd & 7)] = f2bf(O[n][r] * inv);
    }
  __syncthreads();
  #pragma unroll
  for (int p = 0; p < 8; p++){
    int idx = p * 256 + tid;               // 2048 chunks: row(128) x c(16)
    int row = idx >> 4, c = idx & 15;
    u16x8 v = *(const u16x8*)&arena[row * 128 + ((c ^ (row & 15)) * 8)];
    *(u16x8*)&AO[(size_t)(q0 + row) * AOST + head * HD + c * 8] = v;
  }
}

// ---------------- host-side launch ----------------
extern "C" void kernel_launch(void* const* d_in, const int* in_sizes, int n_in,
                              void* d_out, int out_size, void* d_ws, size_t ws_size,
                              hipStream_t stream){
  (void)in_sizes; (void)n_in; (void)out_size; (void)ws_size;
  const float* hs    = (const float*)d_in[0];
  const float* cosv  = (const float*)d_in[1];
  const float* sinv  = (const float*)d_in[2];
  /* d_in[3] attention_mask: pure causal triu(NEG,1) - implemented directly */
  const float* Wq    = (const float*)d_in[4];
  const float* Wk    = (const float*)d_in[5];
  const float* Wv    = (const float*)d_in[6];
  const float* Wo    = (const float*)d_in[7];
  const float* sinkb = (const float*)d_in[8];
  float* out = (float*)d_out;

  char* ws = (char*)d_ws;
  u16* XB    = (u16*)(ws);                  //  8,388,608  X bf16 [2048][2048]
  u16* WQKVB = (u16*)(ws + 8388608);        // 25,165,824  Wqkv bf16 [6144][2048]
  u16* WOB   = (u16*)(ws + 33554432);       // 16,777,216  Wo bf16 [2048][4096]
  u16* QKV   = (u16*)(ws + 50331648);       // 25,165,824  QKV bf16 [2048][6144]
  u16* VT    = (u16*)(ws + 75497472);       //  4,194,304  V^T bf16 [8][128][2048]
  u16* AO    = (u16*)(ws + 79691776);       // 16,777,216  attn out bf16 [2048][4096]

  cvt_all_kernel<<<24576, 256, 0, stream>>>((const f32x4*)hs, (const f32x4*)Wq,
                                            (const f32x4*)Wk, (const f32x4*)Wv,
                                            (const f32x4*)Wo, (u16x4*)ws);

  // fused QKV projection + RoPE + Q-scale(log2e): BM=64 -> 1536 blocks,
  // 3 exact rounds of 512 co-resident (768-block grid was 1.5 rounds: tail)
  gemm_bt_kernel<1, 1, 64, 128><<<dim3(48, 32), 256, 0, stream>>>(XB, WQKVB, QKV, 2048, 6144, 2048, cosv, sinv);

  vtrans_kernel<<<8192, 256, 0, stream>>>(QKV, VT);

  // attention: 512 blocks (128 q-rows each), CU-pair-balanced qt order
  attn_kernel<<<dim3(512), 256, 0, stream>>>(QKV, VT, sinkb, AO);

  // output projection (f32 out): BM=128, BN=64 -> 512 blocks (1 exact round)
  gemm_bt_kernel<0, 0, 128, 64><<<dim3(32, 16), 256, 0, stream>>>(AO, WOB, out, 2048, 2048, 4096, nullptr, nullptr);
}